// Round 8
// baseline (175.217 us; speedup 1.0000x reference)
//
#include <hip/hip_runtime.h>
#include <hip/hip_bf16.h>
#include <stdint.h>

typedef unsigned short u16;
typedef unsigned int u32;
typedef __attribute__((ext_vector_type(8))) __bf16 bf16x8;
typedef __attribute__((ext_vector_type(8))) u16 u16x8;
typedef __attribute__((ext_vector_type(4))) u16 u16x4;
typedef __attribute__((ext_vector_type(4))) float f32x4;
typedef __attribute__((ext_vector_type(4))) u32 u32x4;

#define S_LEN 2048
#define QSCALE 0.180336880f   /* (1/8) * log2(e) */

__device__ __forceinline__ u16 f2bf(float f) {
  u32 u = __builtin_bit_cast(u32, f);
  u32 r = u + 0x7fffu + ((u >> 16) & 1u);   // round-to-nearest-even
  return (u16)(r >> 16);
}
__device__ __forceinline__ float bf2f(u16 h) {
  u32 u = ((u32)h) << 16;
  return __builtin_bit_cast(float, u);
}
__device__ __forceinline__ float ex2(float x) { return __builtin_exp2f(x); }

__device__ __forceinline__ void gload_lds16(const void* g, void* l) {
  __builtin_amdgcn_global_load_lds(
      (const __attribute__((address_space(1))) void*)g,
      (__attribute__((address_space(3))) void*)l, 16, 0, 0);
}

// ---------------------------------------------------------------------------
// fp32 -> bf16 conversion (vectorized, grid-stride)
// ---------------------------------------------------------------------------
__global__ void f2bf_vec(const float* __restrict__ in, u16* __restrict__ out, int n4) {
  int i = blockIdx.x * blockDim.x + threadIdx.x;
  int stride = gridDim.x * blockDim.x;
  for (; i < n4; i += stride) {
    float4 v = ((const float4*)in)[i];
    ushort4 o;
    o.x = f2bf(v.x); o.y = f2bf(v.y); o.z = f2bf(v.z); o.w = f2bf(v.w);
    ((ushort4*)out)[i] = o;
  }
}

// ---------------------------------------------------------------------------
// C = A * B^T + bias.  A:[M,K] bf16, B:[N,K] bf16 (row-major, K contig).
// 128x128 tile, BK=32, 4 waves (2x2). MODE 0: fp32 C0 (ldc).
// MODE 2: QKV split — cols<1024 (Q) -> bf16 C0, scaled by QSCALE;
//         cols in [1024,2048) (K) -> bf16 C0 (ld 2048); cols>=2048 (V) ->
//         transposed bf16 C1 as vt[b*16+h][d][s] (packed 4-row stores).
// ---------------------------------------------------------------------------
template<int MODE>
__global__ __launch_bounds__(256) void gemm_bt(
    const u16* __restrict__ A, const u16* __restrict__ B,
    const float* __restrict__ bias, void* __restrict__ C0,
    u16* __restrict__ C1, int M, int N, int K, int ldc) {
  __shared__ __align__(16) u16 As[128 * 32];
  __shared__ __align__(16) u16 Bs[128 * 32];
  const int tid = threadIdx.x;
  const int wid = tid >> 6, lane = tid & 63;
  const int l15 = lane & 15, l4 = lane >> 4;
  const int wr = wid >> 1, wc = wid & 1;
  const int bm = blockIdx.y * 128, bn = blockIdx.x * 128;

  f32x4 acc[4][4] = {};

  for (int k0 = 0; k0 < K; k0 += 32) {
#pragma unroll
    for (int i = 0; i < 2; ++i) {
      int c = i * 256 + wid * 64 + lane;              // chunk id (16B each)
      int row = c >> 2, kc = c & 3;
      gload_lds16(A + (size_t)(bm + row) * K + k0 + kc * 8,
                  (char*)As + (i * 256 + wid * 64) * 16);
      gload_lds16(B + (size_t)(bn + row) * K + k0 + kc * 8,
                  (char*)Bs + (i * 256 + wid * 64) * 16);
    }
    __syncthreads();

    bf16x8 a[4], b[4];
#pragma unroll
    for (int mi = 0; mi < 4; ++mi)
      a[mi] = __builtin_bit_cast(bf16x8,
          *(const u32x4*)&As[(wr * 64 + mi * 16 + l15) * 32 + l4 * 8]);
#pragma unroll
    for (int ni = 0; ni < 4; ++ni)
      b[ni] = __builtin_bit_cast(bf16x8,
          *(const u32x4*)&Bs[(wc * 64 + ni * 16 + l15) * 32 + l4 * 8]);
#pragma unroll
    for (int mi = 0; mi < 4; ++mi)
#pragma unroll
      for (int ni = 0; ni < 4; ++ni)
        acc[mi][ni] = __builtin_amdgcn_mfma_f32_16x16x32_bf16(
            a[mi], b[ni], acc[mi][ni], 0, 0, 0);
    __syncthreads();
  }

#pragma unroll
  for (int ni = 0; ni < 4; ++ni) {
    int col = bn + wc * 64 + ni * 16 + l15;
    float bv = bias[col];
#pragma unroll
    for (int mi = 0; mi < 4; ++mi) {
      int row = bm + wr * 64 + mi * 16 + l4 * 4;
      if (MODE == 0) {
#pragma unroll
        for (int r = 0; r < 4; ++r)
          ((float*)C0)[(size_t)(row + r) * ldc + col] = acc[mi][ni][r] + bv;
      } else {
        if (col < 2048) {
          float sc = (col < 1024) ? QSCALE : 1.0f;
#pragma unroll
          for (int r = 0; r < 4; ++r)
            ((u16*)C0)[(size_t)(row + r) * 2048 + col] = f2bf((acc[mi][ni][r] + bv) * sc);
        } else {
          u16x4 vv;
#pragma unroll
          for (int r = 0; r < 4; ++r) vv[r] = f2bf(acc[mi][ni][r] + bv);
          int hh = (col - 2048) >> 6, d = (col - 2048) & 63;
          int bb = row >> 11, s = row & 2047;
          *(u16x4*)&C1[(((size_t)(bb * 16 + hh) * 64 + d) << 11) + s] = vv;
        }
      }
    }
  }
}

// ---------------------------------------------------------------------------
// Causal flash attention, QBLK=128 (two 64-row q-groups share each staged
// K/V tile), split-KV (<=16 KV tiles/block), swapped QK^T in-register
// softmax with exact rescale-skip. 24 blocks per bh.
//   i<8:   part0 of j=8+i   (kt 0..15)          -> partial
//   i<16:  part1 of j=23-i  (kt 16..2j+1)       -> partial
//   i<24:  single  j=23-i   (kt 0..2j+1)        -> direct O write
// ---------------------------------------------------------------------------
__global__ __launch_bounds__(256, 3) void attn6(
    const u16* __restrict__ qk, const u16* __restrict__ vt,
    u16* __restrict__ O, u16* __restrict__ pO, float* __restrict__ ML) {
  __shared__ __align__(16) u16 Ks[2][64 * 64];
  __shared__ __align__(16) u16 Vs[2][64 * 64];
  const int tid = threadIdx.x;
  const int wid = tid >> 6, lane = tid & 63;
  const int l15 = lane & 15, l4 = lane >> 4;
  const int i = blockIdx.x, bh = blockIdx.y;
  const int b = bh >> 4, h = bh & 15;

  int j, k0t, mode;
  if (i < 8)       { j = 8 + i;  k0t = 0;  mode = 0; }
  else if (i < 16) { j = 23 - i; k0t = 16; mode = 1; }
  else             { j = 23 - i; k0t = 0;  mode = 2; }
  const int k1t = (mode == 0) ? 15 : (2 * j + 1);
  const int diag0 = 2 * j, diag1 = 2 * j + 1;

  const u16* qkb = qk + (((size_t)b * S_LEN) << 11);
  const u16* vtb = vt + ((size_t)bh << 17);           // 64*2048 per (b,h)
  const int qcol = h * 64, kcol = 1024 + h * 64;

  // staging chunk descriptors: chunk c -> row r = c>>3, swizzled col
  const int c0 = tid, c1 = 256 + tid;
  const int r0 = c0 >> 3, sw0 = ((c0 & 7) ^ (r0 & 7)) << 3;
  const int r1 = c1 >> 3, sw1 = ((c1 & 7) ^ (r1 & 7)) << 3;

  auto stage = [&](int buf, int kt) {
    int kvb = kt << 6;
    gload_lds16(qkb + (((size_t)(kvb + r0)) << 11) + kcol + sw0, (char*)&Ks[buf][0] + c0 * 16);
    gload_lds16(qkb + (((size_t)(kvb + r1)) << 11) + kcol + sw1, (char*)&Ks[buf][0] + c1 * 16);
    gload_lds16(vtb + ((size_t)r0 << 11) + kvb + sw0, (char*)&Vs[buf][0] + c0 * 16);
    gload_lds16(vtb + ((size_t)r1 << 11) + kvb + sw1, (char*)&Vs[buf][0] + c1 * 16);
  };

  // Q fragments (B-operand of swapped mfma), log2-domain pre-scaled.
  bf16x8 qf0[2], qf1[2];
  {
    int rq0 = j * 128 + wid * 16 + l15;
#pragma unroll
    for (int kf = 0; kf < 2; ++kf) {
      qf0[kf] = __builtin_bit_cast(bf16x8,
          *(const u16x8*)&qkb[((size_t)rq0 << 11) + qcol + kf * 32 + l4 * 8]);
      qf1[kf] = __builtin_bit_cast(bf16x8,
          *(const u16x8*)&qkb[((size_t)(rq0 + 64) << 11) + qcol + kf * 32 + l4 * 8]);
    }
  }

  const int qp0 = j * 128 + wid * 16 + l15;   // group0 q-row of this lane
  // bpermute source addresses for the P redistribution (bytes = lane*4)
  const int addrA = (l15 + ((lane & 16) << 1)) << 2;
  const int addrB = addrA + 64;
  const bool hiHalf = (l4 >= 2);

  float m0 = -__builtin_inff(), l0 = 0.f;
  float m1 = -__builtin_inff(), l1 = 0.f;
  f32x4 o0[4] = {}, o1[4] = {};

  // softmax (log2 domain, lane-local kv, exact rescale-skip) + bf16 pack
  auto smx = [&](f32x4* s, float& m_, float& l_, f32x4* o_, u32 (&pk)[4][2]) {
    f32x4 t01 = {fmaxf(s[0][0], s[1][0]), fmaxf(s[0][1], s[1][1]),
                 fmaxf(s[0][2], s[1][2]), fmaxf(s[0][3], s[1][3])};
    f32x4 t23 = {fmaxf(s[2][0], s[3][0]), fmaxf(s[2][1], s[3][1]),
                 fmaxf(s[2][2], s[3][2]), fmaxf(s[2][3], s[3][3])};
    float pm = fmaxf(fmaxf(fmaxf(t01[0], t23[0]), fmaxf(t01[1], t23[1])),
                     fmaxf(fmaxf(t01[2], t23[2]), fmaxf(t01[3], t23[3])));
    pm = fmaxf(pm, __shfl_xor(pm, 16));
    pm = fmaxf(pm, __shfl_xor(pm, 32));
    bool need = pm > m_;
    if (__any((int)need)) {                 // exact: skipped only if es==1
      float nm = fmaxf(m_, pm);
      float es = ex2(m_ - nm);
      m_ = nm;
      l_ *= es;
#pragma unroll
      for (int r = 0; r < 4; ++r) {
        float esr = __shfl(es, (l4 << 4) + l4 * 4 + r);
#pragma unroll
        for (int dt = 0; dt < 4; ++dt) o_[dt][r] *= esr;
      }
    }
#pragma unroll
    for (int nt = 0; nt < 4; ++nt)
#pragma unroll
      for (int r = 0; r < 4; ++r)
        s[nt][r] = ex2(s[nt][r] - m_);
    float ts = ((s[0][0] + s[0][1]) + (s[0][2] + s[0][3]))
             + ((s[1][0] + s[1][1]) + (s[1][2] + s[1][3]))
             + ((s[2][0] + s[2][1]) + (s[2][2] + s[2][3]))
             + ((s[3][0] + s[3][1]) + (s[3][2] + s[3][3]));
    l_ += ts;
#pragma unroll
    for (int nt = 0; nt < 4; ++nt) {
      pk[nt][0] = (u32)f2bf(s[nt][0]) | ((u32)f2bf(s[nt][1]) << 16);
      pk[nt][1] = (u32)f2bf(s[nt][2]) | ((u32)f2bf(s[nt][3]) << 16);
    }
  };

  stage(0, k0t);
  for (int kt = k0t; kt <= k1t; ++kt) {
    const int kvb = kt << 6;
    const int cur = (kt - k0t) & 1;
    __syncthreads();                       // drains stage(cur); guards buf reuse
    if (kt < k1t) stage(cur ^ 1, kt + 1);  // prefetch next tile

    const bool act0 = (kt <= diag0);
    const char* Kc = (const char*)&Ks[cur][0];
    const char* Vc = (const char*)&Vs[cur][0];

    // ---- S^T = K Q^T for both q-groups, sharing K fragments ----
    f32x4 s0[4] = {}, s1[4] = {};
#pragma unroll
    for (int kf = 0; kf < 2; ++kf)
#pragma unroll
      for (int nt = 0; nt < 4; ++nt) {
        int krow = nt * 16 + l15;
        int slot = (kf * 4 + l4) ^ (krow & 7);
        bf16x8 kf8 = __builtin_bit_cast(bf16x8,
            *(const u32x4*)(Kc + krow * 128 + (slot << 4)));
        s1[nt] = __builtin_amdgcn_mfma_f32_16x16x32_bf16(kf8, qf1[kf], s1[nt], 0, 0, 0);
        if (act0)
          s0[nt] = __builtin_amdgcn_mfma_f32_16x16x32_bf16(kf8, qf0[kf], s0[nt], 0, 0, 0);
      }

    // ---- causal masks (diagonal tiles only) ----
    if (kt == diag1) {
#pragma unroll
      for (int nt = 0; nt < 4; ++nt) {
        int kvr = kvb + nt * 16 + l4 * 4;
#pragma unroll
        for (int r = 0; r < 4; ++r)
          if (kvr + r > qp0 + 64) s1[nt][r] = -__builtin_inff();
      }
    }
    if (act0 && kt == diag0) {
#pragma unroll
      for (int nt = 0; nt < 4; ++nt) {
        int kvr = kvb + nt * 16 + l4 * 4;
#pragma unroll
        for (int r = 0; r < 4; ++r)
          if (kvr + r > qp0) s0[nt][r] = -__builtin_inff();
      }
    }

    // ---- softmax + pack ----
    u32 pk0[4][2], pk1[4][2];
    smx(s1, m1, l1, o1, pk1);
    if (act0) smx(s0, m0, l0, o0, pk0);

    // ---- O += P V: bpermute P to A-fragment, V fragments shared ----
#pragma unroll
    for (int kf = 0; kf < 2; ++kf) {
      u32 w1[4], w0[4];
#pragma unroll
      for (int wi = 0; wi < 4; ++wi) {
        int ad = (wi < 2) ? addrA : addrB;
        u32 lo = __builtin_amdgcn_ds_bpermute(ad, (int)pk1[2 * kf][wi & 1]);
        u32 hi = __builtin_amdgcn_ds_bpermute(ad, (int)pk1[2 * kf + 1][wi & 1]);
        w1[wi] = hiHalf ? hi : lo;
      }
      if (act0)
#pragma unroll
        for (int wi = 0; wi < 4; ++wi) {
          int ad = (wi < 2) ? addrA : addrB;
          u32 lo = __builtin_amdgcn_ds_bpermute(ad, (int)pk0[2 * kf][wi & 1]);
          u32 hi = __builtin_amdgcn_ds_bpermute(ad, (int)pk0[2 * kf + 1][wi & 1]);
          w0[wi] = hiHalf ? hi : lo;
        }
      bf16x8 pa1 = __builtin_bit_cast(bf16x8, u32x4{w1[0], w1[1], w1[2], w1[3]});
      bf16x8 pa0 = __builtin_bit_cast(bf16x8, u32x4{w0[0], w0[1], w0[2], w0[3]});
#pragma unroll
      for (int dt = 0; dt < 4; ++dt) {
        int d = dt * 16 + l15;
        int slot = (kf * 4 + l4) ^ (d & 7);
        bf16x8 vf = __builtin_bit_cast(bf16x8,
            *(const u32x4*)(Vc + d * 128 + (slot << 4)));
        o1[dt] = __builtin_amdgcn_mfma_f32_16x16x32_bf16(pa1, vf, o1[dt], 0, 0, 0);
        if (act0)
          o0[dt] = __builtin_amdgcn_mfma_f32_16x16x32_bf16(pa0, vf, o0[dt], 0, 0, 0);
      }
    }
  }

  // ---- epilogue ----
  auto finishl = [&](float l_) {
    float lt = l_ + __shfl_xor(l_, 16);
    lt += __shfl_xor(lt, 32);
    return lt;
  };
  float lt0 = finishl(l0), lt1 = finishl(l1);
  float li0[4], li1[4];
  {
    float v0 = 1.0f / lt0, v1 = 1.0f / lt1;
#pragma unroll
    for (int r = 0; r < 4; ++r) {
      li0[r] = __shfl(v0, (l4 << 4) + l4 * 4 + r);
      li1[r] = __shfl(v1, (l4 << 4) + l4 * 4 + r);
    }
  }

  if (mode == 2) {
#pragma unroll
    for (int dt = 0; dt < 4; ++dt)
#pragma unroll
      for (int r = 0; r < 4; ++r) {
        int tok = j * 128 + wid * 16 + l4 * 4 + r;
        O[(((size_t)(b * S_LEN + tok)) << 10) + h * 64 + dt * 16 + l15] =
            f2bf(o0[dt][r] * li0[r]);
        O[(((size_t)(b * S_LEN + tok + 64)) << 10) + h * 64 + dt * 16 + l15] =
            f2bf(o1[dt][r] * li1[r]);
      }
  } else {
    const int pslot = (((bh << 3) + (j - 8)) << 1) + mode;
    u16* pb = pO + ((size_t)pslot << 13);          // 128x64 u16 per slot
#pragma unroll
    for (int dt = 0; dt < 4; ++dt)
#pragma unroll
      for (int r = 0; r < 4; ++r) {
        int row = wid * 16 + l4 * 4 + r;
        pb[row * 64 + dt * 16 + l15] = f2bf(o0[dt][r] * li0[r]);
        pb[(row + 64) * 64 + dt * 16 + l15] = f2bf(o1[dt][r] * li1[r]);
      }
    if (l4 == 0) {                                 // m/l live at q=l15
      int row = wid * 16 + l15;
      ML[pslot * 256 + row] = m0;
      ML[pslot * 256 + 128 + row] = lt0;
      ML[pslot * 256 + row + 64] = m1;
      ML[pslot * 256 + 128 + row + 64] = lt1;
    }
  }
}

// ---------------------------------------------------------------------------
// Merge the two partials of each j>=8 q-tile (128 rows) into O.
// ---------------------------------------------------------------------------
__global__ __launch_bounds__(256) void combine(
    const u16* __restrict__ pO, const float* __restrict__ ML,
    u16* __restrict__ O) {
  const int jj = blockIdx.x, bh = blockIdx.y;
  const int b = bh >> 4, h = bh & 15;
  const int t = threadIdx.x;
  const int row = t >> 1, cbase = (t & 1) << 5;     // 32 cols per thread
  const int s0 = (((bh << 3) + jj) << 1), s1 = s0 + 1;
  float m0 = ML[s0 * 256 + row], l0 = ML[s0 * 256 + 128 + row];
  float m1 = ML[s1 * 256 + row], l1 = ML[s1 * 256 + 128 + row];
  float m = fmaxf(m0, m1);
  float w0 = l0 * ex2(m0 - m), w1 = l1 * ex2(m1 - m);
  float inv = 1.0f / (w0 + w1);
  w0 *= inv; w1 *= inv;
  const u16* p0 = pO + (((size_t)s0) << 13) + row * 64 + cbase;
  const u16* p1 = pO + (((size_t)s1) << 13) + row * 64 + cbase;
  const int tok = (8 + jj) * 128 + row;
  u16* dst = O + (((size_t)(b * S_LEN + tok)) << 10) + h * 64 + cbase;
#pragma unroll
  for (int half = 0; half < 4; ++half) {
    u16x8 a = *(const u16x8*)(p0 + half * 8);
    u16x8 c = *(const u16x8*)(p1 + half * 8);
    u16x8 o;
#pragma unroll
    for (int jx = 0; jx < 8; ++jx)
      o[jx] = f2bf(w0 * bf2f(a[jx]) + w1 * bf2f(c[jx]));
    *(u16x8*)(dst + half * 8) = o;
  }
}

// ---------------------------------------------------------------------------
extern "C" void kernel_launch(void* const* d_in, const int* in_sizes, int n_in,
                              void* d_out, int out_size, void* d_ws, size_t ws_size,
                              hipStream_t stream) {
  const float* x    = (const float*)d_in[0];
  const float* Wqkv = (const float*)d_in[1];
  const float* bqkv = (const float*)d_in[2];
  const float* Wout = (const float*)d_in[3];
  const float* bout = (const float*)d_in[4];
  float* out = (float*)d_out;

  // workspace layout (u16 elems): ~51 MiB total
  u16* xb    = (u16*)d_ws;            // 4,194,304   (dead after QKV GEMM)
  u16* wqkvb = xb + 4194304;          // 3,145,728   (dead after QKV GEMM)
  u16* woutb = wqkvb + 3145728;       // 1,048,576
  u16* qkb   = woutb + 1048576;       // 8,388,608  (Q|K, [4096][2048])
  u16* vtb   = qkb + 8388608;         // 4,194,304  (V^T, [32][64][2048])
  u16* ob    = vtb + 4194304;         // 4,194,304
  // attention partials alias the dead xb/wqkvb regions:
  u16*   pO = xb;                     // 512 slots x 128x64 bf16 = 4,194,304 u16
  float* ML = (float*)wqkvb;          // 512 slots x 256 f32     = 131,072 f32

  f2bf_vec<<<1024, 256, 0, stream>>>(x,    xb,    4194304 / 4);
  f2bf_vec<<<1024, 256, 0, stream>>>(Wqkv, wqkvb, 3145728 / 4);
  f2bf_vec<<<512,  256, 0, stream>>>(Wout, woutb, 1048576 / 4);

  gemm_bt<2><<<dim3(24, 32), 256, 0, stream>>>(xb, wqkvb, bqkv, qkb, vtb,
                                               4096, 3072, 1024, 0);
  attn6<<<dim3(24, 32), 256, 0, stream>>>(qkb, vtb, ob, pO, ML);
  combine<<<dim3(8, 32), 256, 0, stream>>>(pO, ML, ob);
  gemm_bt<0><<<dim3(8, 32), 256, 0, stream>>>(ob, woutb, bout, out, nullptr,
                                              4096, 1024, 1024, 1024);
}

// Round 9
// 151.367 us; speedup vs baseline: 1.1576x; 1.1576x over previous
//
#include <hip/hip_runtime.h>
#include <hip/hip_bf16.h>
#include <stdint.h>

typedef unsigned short u16;
typedef unsigned int u32;
typedef __attribute__((ext_vector_type(8))) __bf16 bf16x8;
typedef __attribute__((ext_vector_type(8))) u16 u16x8;
typedef __attribute__((ext_vector_type(4))) u16 u16x4;
typedef __attribute__((ext_vector_type(4))) float f32x4;
typedef __attribute__((ext_vector_type(4))) u32 u32x4;

#define S_LEN 2048
#define QSCALE 0.180336880f   /* (1/8) * log2(e) */

__device__ __forceinline__ u16 f2bf(float f) {
  u32 u = __builtin_bit_cast(u32, f);
  u32 r = u + 0x7fffu + ((u >> 16) & 1u);   // round-to-nearest-even
  return (u16)(r >> 16);
}
__device__ __forceinline__ float bf2f(u16 h) {
  u32 u = ((u32)h) << 16;
  return __builtin_bit_cast(float, u);
}
__device__ __forceinline__ float ex2(float x) { return __builtin_exp2f(x); }

__device__ __forceinline__ void gload_lds16(const void* g, void* l) {
  __builtin_amdgcn_global_load_lds(
      (const __attribute__((address_space(1))) void*)g,
      (__attribute__((address_space(3))) void*)l, 16, 0, 0);
}

// ---------------------------------------------------------------------------
// fused fp32 -> bf16 conversion of x | Wqkv | Wout (one launch)
// ---------------------------------------------------------------------------
#define N4_X 1048576
#define N4_WQKV 786432
#define N4_WOUT 262144
__global__ void f2bf_all(const float* __restrict__ x, const float* __restrict__ wq,
                         const float* __restrict__ wo, u16* __restrict__ xb,
                         u16* __restrict__ wqb, u16* __restrict__ wob) {
  int i = blockIdx.x * blockDim.x + threadIdx.x;
  int stride = gridDim.x * blockDim.x;
  const int total = N4_X + N4_WQKV + N4_WOUT;
  for (; i < total; i += stride) {
    const float4* src; ushort4* dst; int k;
    if (i < N4_X) { src = (const float4*)x; dst = (ushort4*)xb; k = i; }
    else if (i < N4_X + N4_WQKV) { src = (const float4*)wq; dst = (ushort4*)wqb; k = i - N4_X; }
    else { src = (const float4*)wo; dst = (ushort4*)wob; k = i - N4_X - N4_WQKV; }
    float4 v = src[k];
    ushort4 o;
    o.x = f2bf(v.x); o.y = f2bf(v.y); o.z = f2bf(v.z); o.w = f2bf(v.w);
    dst[k] = o;
  }
}

// ---------------------------------------------------------------------------
// C = A * B^T + bias.  A:[M,K] bf16, B:[N,K] bf16 (row-major, K contig).
// 128x128 tile, BK=32, 4 waves (2x2). MODE 0: fp32 C0 (ldc).
// MODE 2: QKV split — cols<1024 (Q) -> bf16 C0, scaled by QSCALE;
//         cols in [1024,2048) (K) -> bf16 C0 (ld 2048); cols>=2048 (V) ->
//         transposed bf16 C1 as vt[b*16+h][d][s] (packed 4-row stores).
// ---------------------------------------------------------------------------
template<int MODE>
__global__ __launch_bounds__(256) void gemm_bt(
    const u16* __restrict__ A, const u16* __restrict__ B,
    const float* __restrict__ bias, void* __restrict__ C0,
    u16* __restrict__ C1, int M, int N, int K, int ldc) {
  __shared__ __align__(16) u16 As[128 * 32];
  __shared__ __align__(16) u16 Bs[128 * 32];
  const int tid = threadIdx.x;
  const int wid = tid >> 6, lane = tid & 63;
  const int l15 = lane & 15, l4 = lane >> 4;
  const int wr = wid >> 1, wc = wid & 1;
  const int bm = blockIdx.y * 128, bn = blockIdx.x * 128;

  f32x4 acc[4][4] = {};

  for (int k0 = 0; k0 < K; k0 += 32) {
#pragma unroll
    for (int i = 0; i < 2; ++i) {
      int c = i * 256 + wid * 64 + lane;              // chunk id (16B each)
      int row = c >> 2, kc = c & 3;
      gload_lds16(A + (size_t)(bm + row) * K + k0 + kc * 8,
                  (char*)As + (i * 256 + wid * 64) * 16);
      gload_lds16(B + (size_t)(bn + row) * K + k0 + kc * 8,
                  (char*)Bs + (i * 256 + wid * 64) * 16);
    }
    __syncthreads();

    bf16x8 a[4], b[4];
#pragma unroll
    for (int mi = 0; mi < 4; ++mi)
      a[mi] = __builtin_bit_cast(bf16x8,
          *(const u32x4*)&As[(wr * 64 + mi * 16 + l15) * 32 + l4 * 8]);
#pragma unroll
    for (int ni = 0; ni < 4; ++ni)
      b[ni] = __builtin_bit_cast(bf16x8,
          *(const u32x4*)&Bs[(wc * 64 + ni * 16 + l15) * 32 + l4 * 8]);
#pragma unroll
    for (int mi = 0; mi < 4; ++mi)
#pragma unroll
      for (int ni = 0; ni < 4; ++ni)
        acc[mi][ni] = __builtin_amdgcn_mfma_f32_16x16x32_bf16(
            a[mi], b[ni], acc[mi][ni], 0, 0, 0);
    __syncthreads();
  }

#pragma unroll
  for (int ni = 0; ni < 4; ++ni) {
    int col = bn + wc * 64 + ni * 16 + l15;
    float bv = bias[col];
#pragma unroll
    for (int mi = 0; mi < 4; ++mi) {
      int row = bm + wr * 64 + mi * 16 + l4 * 4;
      if (MODE == 0) {
#pragma unroll
        for (int r = 0; r < 4; ++r)
          ((float*)C0)[(size_t)(row + r) * ldc + col] = acc[mi][ni][r] + bv;
      } else {
        if (col < 2048) {
          float sc = (col < 1024) ? QSCALE : 1.0f;
#pragma unroll
          for (int r = 0; r < 4; ++r)
            ((u16*)C0)[(size_t)(row + r) * 2048 + col] = f2bf((acc[mi][ni][r] + bv) * sc);
        } else {
          u16x4 vv;
#pragma unroll
          for (int r = 0; r < 4; ++r) vv[r] = f2bf(acc[mi][ni][r] + bv);
          int hh = (col - 2048) >> 6, d = (col - 2048) & 63;
          int bb = row >> 11, s = row & 2047;
          *(u16x4*)&C1[(((size_t)(bb * 16 + hh) * 64 + d) << 11) + s] = vv;
        }
      }
    }
  }
}

// ---------------------------------------------------------------------------
// Causal flash attention, split-KV, swapped QK^T (r7 structure, proven):
// S^T = K Q^T so each lane owns one q-row (q = l15) with kv lane-local ->
// in-register max/sum trees, scalar m/l, P redistributed via ds_bpermute.
// This round: 5 blocks/CU allowed + exact rescale-skip.
// ---------------------------------------------------------------------------
__global__ __launch_bounds__(256, 5) void attn5(
    const u16* __restrict__ qk, const u16* __restrict__ vt,
    u16* __restrict__ O, u16* __restrict__ pO, float* __restrict__ ML) {
  __shared__ __align__(16) u16 Ks[2][64 * 64];
  __shared__ __align__(16) u16 Vs[2][64 * 64];
  const int tid = threadIdx.x;
  const int wid = tid >> 6, lane = tid & 63;
  const int l15 = lane & 15, l4 = lane >> 4;
  const int i = blockIdx.x, bh = blockIdx.y;
  const int b = bh >> 4, h = bh & 15;

  // decode (qt, kt-range, mode); ordered roughly longest-first
  int qt, k0t, mode;
  if (i < 16)      { qt = 16 + i;  k0t = 0;  mode = 0; }   // part0, len 16
  else if (i < 32) { qt = 47 - i;  k0t = 16; mode = 1; }   // part1, len qt-15
  else             { qt = 47 - i;  k0t = 0;  mode = 2; }   // single, len qt+1
  const int k1t = (mode == 0) ? 15 : qt;

  const u16* qkb = qk + (((size_t)b * S_LEN) << 11);
  const u16* vtb = vt + ((size_t)bh << 17);           // 64*2048 per (b,h)
  const int qcol = h * 64, kcol = 1024 + h * 64;

  // staging chunk descriptors: chunk c -> row r = c>>3, swizzled col
  const int c0 = tid, c1 = 256 + tid;
  const int r0 = c0 >> 3, sw0 = ((c0 & 7) ^ (r0 & 7)) << 3;
  const int r1 = c1 >> 3, sw1 = ((c1 & 7) ^ (r1 & 7)) << 3;

  auto stage = [&](int buf, int kt) {
    int kvb = kt << 6;
    gload_lds16(qkb + (((size_t)(kvb + r0)) << 11) + kcol + sw0, (char*)&Ks[buf][0] + c0 * 16);
    gload_lds16(qkb + (((size_t)(kvb + r1)) << 11) + kcol + sw1, (char*)&Ks[buf][0] + c1 * 16);
    gload_lds16(vtb + ((size_t)r0 << 11) + kvb + sw0, (char*)&Vs[buf][0] + c0 * 16);
    gload_lds16(vtb + ((size_t)r1 << 11) + kvb + sw1, (char*)&Vs[buf][0] + c1 * 16);
  };

  // Q fragments: B-operand of swapped mfma = Q[q=l15][d=l4*8+j]
  bf16x8 qf[2];
  {
    int rq = qt * 64 + wid * 16 + l15;
#pragma unroll
    for (int kf = 0; kf < 2; ++kf)
      qf[kf] = __builtin_bit_cast(bf16x8,
          *(const u16x8*)&qkb[((size_t)rq << 11) + qcol + kf * 32 + l4 * 8]);
  }

  const int qpos = qt * 64 + wid * 16 + l15;   // this lane's q-row
  // bpermute source addresses for the P redistribution (bytes = lane*4)
  const int addrA = (l15 + ((lane & 16) << 1)) << 2;
  const int addrB = addrA + 64;
  const bool hiHalf = (l4 >= 2);

  float m_ = -__builtin_inff(), l_ = 0.f;
  f32x4 o_[4] = {};

  stage(0, k0t);
  for (int kt = k0t; kt <= k1t; ++kt) {
    const int kvb = kt << 6;
    const int cur = (kt - k0t) & 1;
    __syncthreads();                       // drains stage(cur); guards buf reuse
    if (kt < k1t) stage(cur ^ 1, kt + 1);  // prefetch next tile

    const char* Kc = (const char*)&Ks[cur][0];
    const char* Vc = (const char*)&Vs[cur][0];

    // ---- S^T = K Q^T (log2 domain): s[nt][r] = S[q=l15][kv=nt*16+l4*4+r] --
    f32x4 s[4] = {};
#pragma unroll
    for (int kf = 0; kf < 2; ++kf)
#pragma unroll
      for (int nt = 0; nt < 4; ++nt) {
        int krow = nt * 16 + l15;
        int slot = (kf * 4 + l4) ^ (krow & 7);
        bf16x8 kf8 = __builtin_bit_cast(bf16x8,
            *(const u32x4*)(Kc + krow * 128 + (slot << 4)));
        s[nt] = __builtin_amdgcn_mfma_f32_16x16x32_bf16(kf8, qf[kf], s[nt], 0, 0, 0);
      }

    // ---- causal mask (diagonal tile only; kv = kvb+nt*16+l4*4+r) ----
    if (kt == qt) {
#pragma unroll
      for (int nt = 0; nt < 4; ++nt) {
        int kvr = kvb + nt * 16 + l4 * 4;
#pragma unroll
        for (int r = 0; r < 4; ++r)
          if (kvr + r > qpos) s[nt][r] = -__builtin_inff();
      }
    }

    // ---- online softmax: in-register trees + 2 shfl; exact rescale-skip ----
    {
      f32x4 t01 = {fmaxf(s[0][0], s[1][0]), fmaxf(s[0][1], s[1][1]),
                   fmaxf(s[0][2], s[1][2]), fmaxf(s[0][3], s[1][3])};
      f32x4 t23 = {fmaxf(s[2][0], s[3][0]), fmaxf(s[2][1], s[3][1]),
                   fmaxf(s[2][2], s[3][2]), fmaxf(s[2][3], s[3][3])};
      float pm = fmaxf(fmaxf(fmaxf(t01[0], t23[0]), fmaxf(t01[1], t23[1])),
                       fmaxf(fmaxf(t01[2], t23[2]), fmaxf(t01[3], t23[3])));
      pm = fmaxf(pm, __shfl_xor(pm, 16));
      pm = fmaxf(pm, __shfl_xor(pm, 32));
      bool need = pm > m_;
      if (__any((int)need)) {              // exact: skipped only when es==1
        float nm = fmaxf(m_, pm);
        float es = ex2(m_ - nm);
        m_ = nm;
        l_ *= es;
#pragma unroll
        for (int r = 0; r < 4; ++r) {
          float esr = __shfl(es, (l4 << 4) + l4 * 4 + r);
#pragma unroll
          for (int dt = 0; dt < 4; ++dt) o_[dt][r] *= esr;
        }
      }
#pragma unroll
      for (int nt = 0; nt < 4; ++nt)
#pragma unroll
        for (int r = 0; r < 4; ++r)
          s[nt][r] = ex2(s[nt][r] - m_);
      float ts = ((s[0][0] + s[0][1]) + (s[0][2] + s[0][3]))
               + ((s[1][0] + s[1][1]) + (s[1][2] + s[1][3]))
               + ((s[2][0] + s[2][1]) + (s[2][2] + s[2][3]))
               + ((s[3][0] + s[3][1]) + (s[3][2] + s[3][3]));
      l_ += ts;
    }

    // ---- pack P to bf16 pairs: pk[nt][w] = kv {nt*16+l4*4+2w, +1} ----
    u32 pk[4][2];
#pragma unroll
    for (int nt = 0; nt < 4; ++nt) {
      pk[nt][0] = (u32)f2bf(s[nt][0]) | ((u32)f2bf(s[nt][1]) << 16);
      pk[nt][1] = (u32)f2bf(s[nt][2]) | ((u32)f2bf(s[nt][3]) << 16);
    }

    // ---- O += P V: redistribute P to A-fragment via ds_bpermute ----
#pragma unroll
    for (int kf = 0; kf < 2; ++kf) {
      u32 w[4];
#pragma unroll
      for (int wi = 0; wi < 4; ++wi) {
        int ad = (wi < 2) ? addrA : addrB;
        u32 lo = __builtin_amdgcn_ds_bpermute(ad, (int)pk[2 * kf][wi & 1]);
        u32 hi = __builtin_amdgcn_ds_bpermute(ad, (int)pk[2 * kf + 1][wi & 1]);
        w[wi] = hiHalf ? hi : lo;
      }
      bf16x8 pa = __builtin_bit_cast(bf16x8, u32x4{w[0], w[1], w[2], w[3]});
#pragma unroll
      for (int dt = 0; dt < 4; ++dt) {
        int d = dt * 16 + l15;
        int slot = (kf * 4 + l4) ^ (d & 7);
        bf16x8 vf = __builtin_bit_cast(bf16x8,
            *(const u32x4*)(Vc + d * 128 + (slot << 4)));
        o_[dt] = __builtin_amdgcn_mfma_f32_16x16x32_bf16(pa, vf, o_[dt], 0, 0, 0);
      }
    }
  }

  // ---- epilogue: finish l reduce (across l4), normalize, store ----
  float lt = l_ + __shfl_xor(l_, 16);
  lt += __shfl_xor(lt, 32);
  float linv = 1.0f / lt;
  float li4[4];
#pragma unroll
  for (int r = 0; r < 4; ++r)
    li4[r] = __shfl(linv, (l4 << 4) + l4 * 4 + r);

  if (mode == 2) {
#pragma unroll
    for (int dt = 0; dt < 4; ++dt)
#pragma unroll
      for (int r = 0; r < 4; ++r) {
        float val = o_[dt][r] * li4[r];
        int tok = qt * 64 + wid * 16 + l4 * 4 + r;
        O[(((size_t)(b * S_LEN + tok)) << 10) + h * 64 + dt * 16 + l15] = f2bf(val);
      }
  } else {
    const int pslot = (((bh << 4) + (qt - 16)) << 1) + mode;
    u16* pb = pO + ((size_t)pslot << 12);
#pragma unroll
    for (int dt = 0; dt < 4; ++dt)
#pragma unroll
      for (int r = 0; r < 4; ++r) {
        int row = wid * 16 + l4 * 4 + r;
        pb[row * 64 + dt * 16 + l15] = f2bf(o_[dt][r] * li4[r]);
      }
    if (l4 == 0) {                      // m_/lt live at q = l15, uniform in l4
      ML[pslot * 128 + wid * 16 + l15] = m_;
      ML[pslot * 128 + 64 + wid * 16 + l15] = lt;
    }
  }
}

// ---------------------------------------------------------------------------
// Merge the two partials of each qt>=16 q-tile into O.
// ---------------------------------------------------------------------------
__global__ __launch_bounds__(256) void combine(
    const u16* __restrict__ pO, const float* __restrict__ ML,
    u16* __restrict__ O) {
  const int qi = blockIdx.x, bh = blockIdx.y;
  const int b = bh >> 4, h = bh & 15;
  const int t = threadIdx.x;
  const int row = t >> 2, cblk = (t & 3) << 4;      // 16 cols per thread
  const int s0 = (((bh << 4) + qi) << 1), s1 = s0 + 1;
  float m0 = ML[s0 * 128 + row], l0 = ML[s0 * 128 + 64 + row];
  float m1 = ML[s1 * 128 + row], l1 = ML[s1 * 128 + 64 + row];
  float m = fmaxf(m0, m1);
  float w0 = l0 * ex2(m0 - m), w1 = l1 * ex2(m1 - m);
  float inv = 1.0f / (w0 + w1);
  w0 *= inv; w1 *= inv;
  const u16* p0 = pO + (((size_t)s0) << 12) + row * 64 + cblk;
  const u16* p1 = pO + (((size_t)s1) << 12) + row * 64 + cblk;
  const int tok = (16 + qi) * 64 + row;
  u16* dst = O + (((size_t)(b * S_LEN + tok)) << 10) + h * 64 + cblk;
#pragma unroll
  for (int half = 0; half < 2; ++half) {
    u16x8 a = *(const u16x8*)(p0 + half * 8);
    u16x8 c = *(const u16x8*)(p1 + half * 8);
    u16x8 o;
#pragma unroll
    for (int j = 0; j < 8; ++j)
      o[j] = f2bf(w0 * bf2f(a[j]) + w1 * bf2f(c[j]));
    *(u16x8*)(dst + half * 8) = o;
  }
}

// ---------------------------------------------------------------------------
extern "C" void kernel_launch(void* const* d_in, const int* in_sizes, int n_in,
                              void* d_out, int out_size, void* d_ws, size_t ws_size,
                              hipStream_t stream) {
  const float* x    = (const float*)d_in[0];
  const float* Wqkv = (const float*)d_in[1];
  const float* bqkv = (const float*)d_in[2];
  const float* Wout = (const float*)d_in[3];
  const float* bout = (const float*)d_in[4];
  float* out = (float*)d_out;

  // workspace layout (u16 elems): ~51 MiB total
  u16* xb    = (u16*)d_ws;            // 4,194,304   (dead after QKV GEMM)
  u16* wqkvb = xb + 4194304;          // 3,145,728   (dead after QKV GEMM)
  u16* woutb = wqkvb + 3145728;       // 1,048,576
  u16* qkb   = woutb + 1048576;       // 8,388,608  (Q|K, [4096][2048])
  u16* vtb   = qkb + 8388608;         // 4,194,304  (V^T, [32][64][2048])
  u16* ob    = vtb + 4194304;         // 4,194,304
  // attention partials alias the dead xb/wqkvb regions:
  u16*   pO = xb;                     // 1024 slots x 64x64 bf16 = 4,194,304 u16
  float* ML = (float*)wqkvb;          // 1024 slots x 128 f32    = 131,072 f32

  f2bf_all<<<2048, 256, 0, stream>>>(x, Wqkv, Wout, xb, wqkvb, woutb);

  gemm_bt<2><<<dim3(24, 32), 256, 0, stream>>>(xb, wqkvb, bqkv, qkb, vtb,
                                               4096, 3072, 1024, 0);
  attn5<<<dim3(48, 32), 256, 0, stream>>>(qkb, vtb, ob, pO, ML);
  combine<<<dim3(16, 32), 256, 0, stream>>>(pO, ML, ob);
  gemm_bt<0><<<dim3(8, 32), 256, 0, stream>>>(ob, woutb, bout, out, nullptr,
                                              4096, 1024, 1024, 1024);
}